// Round 1
// baseline (815.795 us; speedup 1.0000x reference)
//
#include <hip/hip_runtime.h>

#define Bsz 512
#define Ssz 512
#define Isz 32
#define Hsz 128
#define NG  512   // 4*H
#define BB  2     // batch rows per workgroup
#define LOG2E 1.44269504088896340736f

typedef __attribute__((ext_vector_type(8))) short bf16x8;
typedef __attribute__((ext_vector_type(4))) float f32x4;
typedef __attribute__((ext_vector_type(2))) float f32x2;

// float -> bf16 (round-to-nearest-even), raw ushort
__device__ __forceinline__ unsigned short f2bf(float f){
  unsigned u = __float_as_uint(f);
  return (unsigned short)((u + 0x7FFFu + ((u >> 16) & 1u)) >> 16);
}

// pre-activation already scaled by log2(e):  sigmoid(x) = 1/(1+2^-xp)
__device__ __forceinline__ float sigm_p(float xp){
  return __builtin_amdgcn_rcpf(1.f + __builtin_amdgcn_exp2f(-xp));
}
// pre-activation already scaled by 2*log2(e): tanh(x) = 1 - 2/(1+2^xp2)
__device__ __forceinline__ float tanh_p(float xp2){
  return 1.f - 2.f * __builtin_amdgcn_rcpf(1.f + __builtin_amdgcn_exp2f(xp2));
}

// Load one B-fragment (B[k][n] = W[n][k]) for mfma_f32_16x16x32_bf16.
// lane: n = (tile)*16 + (lane&15), k = k0 + e, e=0..7 (k0 includes quad*8).
// scaled!=0: multiply rows by log2e (i,f,o) or 2*log2e (g rows 256..383).
__device__ __forceinline__ bf16x8 ldw(const float* W, int K, int n, int k0, int scaled){
  float s = 1.f;
  if (scaled) s = ((n >> 7) == 2) ? 2.f*LOG2E : LOG2E;
  const float* p = W + (size_t)n*K + k0;
  bf16x8 r;
#pragma unroll
  for (int e=0;e<8;++e) r[e] = (short)f2bf(p[e]*s);
  return r;
}

__device__ __forceinline__ bf16x8 ldwsum(const float* Wa, const float* Wb, int n, int k0){
  float s = ((n >> 7) == 2) ? 2.f*LOG2E : LOG2E;
  const float* pa = Wa + (size_t)n*Hsz + k0;
  const float* pb = Wb + (size_t)n*Hsz + k0;
  bf16x8 r;
#pragma unroll
  for (int e=0;e<8;++e) r[e] = (short)f2bf((pa[e]+pb[e])*s);
  return r;
}

__global__ __launch_bounds__(256, 1) void lstm_ae(
    const float* __restrict__ x,
    const float* __restrict__ eWih, const float* __restrict__ eWhh,
    const float* __restrict__ ebih, const float* __restrict__ ebhh,
    const float* __restrict__ dWih, const float* __restrict__ dWhh,
    const float* __restrict__ dbih, const float* __restrict__ dbhh,
    const float* __restrict__ fcW,  const float* __restrict__ fcb,
    float* __restrict__ out)
{
  // gates scratch: word index = 6*col + row  (stride 6 -> b64-aligned writes,
  // conflict-free act reads).  h buffer: [16 rows][128+8] bf16, stride 272B.
  __shared__ __attribute__((aligned(16))) float gbuf[NG*6];
  __shared__ __attribute__((aligned(16))) unsigned short hbuf[16*136];

  const int tid  = threadIdx.x;
  const int lane = tid & 63;
  const int wv   = tid >> 6;       // wave 0..3, owns gate n-tiles 8w..8w+7
  const int c16  = lane & 15;
  const int quad = lane >> 4;
  const int wg   = blockIdx.x;
  const int bg0  = wg * BB;

  for (int idx = tid; idx < 16*136; idx += 256) hbuf[idx] = 0;
  // activation-thread mapping: 256 threads x 1 (b,k) pair
  const int ab = tid & 1;          // batch row within WG
  const int ak = tid >> 1;         // h column 0..127
  float cst = 0.f;                 // persistent cell state for (ab, ak)
  __syncthreads();

  // ---------------- encoder weights -> registers ----------------
  float bias_e[8];
  bf16x8 wh[8][4], wx[8];
#pragma unroll
  for (int j=0;j<8;++j){
    int n = (wv*8+j)*16 + c16;
    int kq = quad*8;
#pragma unroll
    for (int kt=0;kt<4;++kt) wh[j][kt] = ldw(eWhh, Hsz, n, kt*32+kq, 1);
    wx[j] = ldw(eWih, Isz, n, kq, 1);
    float s = ((n>>7)==2) ? 2.f*LOG2E : LOG2E;
    bias_e[j] = (ebih[n]+ebhh[n]) * s;
  }

  auto ld_ah = [&](bf16x8* ah){
#pragma unroll
    for (int kt=0;kt<4;++kt)
      ah[kt] = *(const bf16x8*)(hbuf + c16*136 + kt*32 + quad*8);
  };
  auto wr_gates = [&](f32x4* acc){
    if (quad == 0){
#pragma unroll
      for (int j=0;j<8;++j){
        int col = (wv*8+j)*16 + c16;
        f32x2 g2 = {acc[j][0], acc[j][1]};      // rows 0,1 (BB=2)
        *(f32x2*)(gbuf + 6*col) = g2;
      }
    }
  };
  auto act = [&](bool upd){
    float pi = gbuf[6*(0*Hsz+ak)+ab];
    float pf = gbuf[6*(1*Hsz+ak)+ab];
    float pg = gbuf[6*(2*Hsz+ak)+ab];
    float po = gbuf[6*(3*Hsz+ak)+ab];
    float iv = sigm_p(pi);
    float fv = sigm_p(pf);
    float ov = sigm_p(po);
    float gv = tanh_p(pg);
    float cn = fv*cst + iv*gv;
    if (upd) cst = cn;                          // decoder: cst stays enc_c
    float hh = ov * tanh_p(cn*(2.f*LOG2E));
    hbuf[ab*136 + ak] = f2bf(hh);
  };

  // x prefetch (A-frag source for the 5th k-tile)
  const int bl = (c16 < BB) ? c16 : (BB-1);     // clamp pad rows
  const float* xbase = x + ((size_t)(bg0+bl)*Ssz)*Isz + quad*8;
  f32x4 xva = *(const f32x4*)(xbase);
  f32x4 xvb = *(const f32x4*)(xbase+4);

  // ---------------- encoder loop ----------------
  for (int t=0; t<Ssz; ++t){
    bf16x8 ax;
#pragma unroll
    for (int e=0;e<4;++e){ ax[e]=(short)f2bf(xva[e]); ax[e+4]=(short)f2bf(xvb[e]); }
    if (t+1 < Ssz){
      const float* p = xbase + (size_t)(t+1)*Isz;
      xva = *(const f32x4*)p; xvb = *(const f32x4*)(p+4);
    }
    bf16x8 ah[4]; ld_ah(ah);
    f32x4 acc[8];
#pragma unroll
    for (int j=0;j<8;++j){ f32x4 b4 = {bias_e[j],bias_e[j],bias_e[j],bias_e[j]}; acc[j] = b4; }
#pragma unroll
    for (int j=0;j<8;++j){
#pragma unroll
      for (int kt=0;kt<4;++kt)
        acc[j] = __builtin_amdgcn_mfma_f32_16x16x32_bf16(ah[kt], wh[j][kt], acc[j], 0,0,0);
      acc[j] = __builtin_amdgcn_mfma_f32_16x16x32_bf16(ax, wx[j], acc[j], 0,0,0);
    }
    wr_gates(acc);
    __syncthreads();
    act(true);
    __syncthreads();
  }

  // ---------------- decoder ----------------
  float bias_d[8];
#pragma unroll
  for (int j=0;j<8;++j){
    int n = (wv*8+j)*16 + c16;
    float s = ((n>>7)==2) ? 2.f*LOG2E : LOG2E;
    bias_d[j] = (dbih[n]+dbhh[n]) * s;
  }

  // step 0: inp = 0, h = enc_h  ->  gates = enc_h @ dWhh^T + b
  {
    bf16x8 wd[8][4];
#pragma unroll
    for (int j=0;j<8;++j){
      int n = (wv*8+j)*16 + c16;
#pragma unroll
      for (int kt=0;kt<4;++kt) wd[j][kt] = ldw(dWhh, Hsz, n, kt*32+quad*8, 1);
    }
    bf16x8 ah[4]; ld_ah(ah);
    f32x4 acc[8];
#pragma unroll
    for (int j=0;j<8;++j){ f32x4 b4 = {bias_d[j],bias_d[j],bias_d[j],bias_d[j]}; acc[j] = b4; }
#pragma unroll
    for (int j=0;j<8;++j){
#pragma unroll
      for (int kt=0;kt<4;++kt)
        acc[j] = __builtin_amdgcn_mfma_f32_16x16x32_bf16(ah[kt], wd[j][kt], acc[j], 0,0,0);
    }
    wr_gates(acc);
    __syncthreads();
    act(false);
    __syncthreads();
  }

  // steps >=1: inp == h  ->  gates = h @ (dWih+dWhh)^T + b
  bf16x8 ws[8][4];
#pragma unroll
  for (int j=0;j<8;++j){
    int n = (wv*8+j)*16 + c16;
#pragma unroll
    for (int kt=0;kt<4;++kt) ws[j][kt] = ldwsum(dWih, dWhh, n, kt*32+quad*8);
  }
  bf16x8 wf[4];
  float bias_f = 0.f;
  if (wv < 2){                                   // waves 0,1 own fc tiles
    int n = wv*16 + c16;                         // output col 0..31
#pragma unroll
    for (int kt=0;kt<4;++kt) wf[kt] = ldw(fcW, Hsz, n, kt*32+quad*8, 0);
    bias_f = fcb[n];
  }

  for (int t=1; t<Ssz; ++t){
    bf16x8 ah[4]; ld_ah(ah);                     // h(t-1)
    if (wv < 2){                                 // frame(t-1) = h(t-1)@fcW^T + b
      f32x4 fa = {bias_f,bias_f,bias_f,bias_f};
#pragma unroll
      for (int kt=0;kt<4;++kt)
        fa = __builtin_amdgcn_mfma_f32_16x16x32_bf16(ah[kt], wf[kt], fa, 0,0,0);
      if (quad == 0){
#pragma unroll
        for (int r=0;r<BB;++r)
          out[((size_t)(bg0+r)*Ssz + (t-1))*Isz + wv*16 + c16] = fa[r];
      }
    }
    f32x4 acc[8];
#pragma unroll
    for (int j=0;j<8;++j){ f32x4 b4 = {bias_d[j],bias_d[j],bias_d[j],bias_d[j]}; acc[j] = b4; }
#pragma unroll
    for (int j=0;j<8;++j){
#pragma unroll
      for (int kt=0;kt<4;++kt)
        acc[j] = __builtin_amdgcn_mfma_f32_16x16x32_bf16(ah[kt], ws[j][kt], acc[j], 0,0,0);
    }
    wr_gates(acc);
    __syncthreads();
    act(false);
    __syncthreads();
  }

  // epilogue: frame for s = 511
  {
    bf16x8 ah[4]; ld_ah(ah);
    if (wv < 2){
      f32x4 fa = {bias_f,bias_f,bias_f,bias_f};
#pragma unroll
      for (int kt=0;kt<4;++kt)
        fa = __builtin_amdgcn_mfma_f32_16x16x32_bf16(ah[kt], wf[kt], fa, 0,0,0);
      if (quad == 0){
#pragma unroll
        for (int r=0;r<BB;++r)
          out[((size_t)(bg0+r)*Ssz + (Ssz-1))*Isz + wv*16 + c16] = fa[r];
      }
    }
  }
}

extern "C" void kernel_launch(void* const* d_in, const int* in_sizes, int n_in,
                              void* d_out, int out_size, void* d_ws, size_t ws_size,
                              hipStream_t stream) {
  const float* x    = (const float*)d_in[0];
  const float* eWih = (const float*)d_in[1];
  const float* eWhh = (const float*)d_in[2];
  const float* ebih = (const float*)d_in[3];
  const float* ebhh = (const float*)d_in[4];
  const float* dWih = (const float*)d_in[5];
  const float* dWhh = (const float*)d_in[6];
  const float* dbih = (const float*)d_in[7];
  const float* dbhh = (const float*)d_in[8];
  const float* fcW  = (const float*)d_in[9];
  const float* fcb  = (const float*)d_in[10];
  float* outp = (float*)d_out;
  (void)d_ws; (void)ws_size; (void)in_sizes; (void)n_in; (void)out_size;
  lstm_ae<<<dim3(Bsz/BB), dim3(256), 0, stream>>>(
      x, eWih, eWhh, ebih, ebhh, dWih, dWhh, dbih, dbhh, fcW, fcb, outp);
}

// Round 2
// 790.150 us; speedup vs baseline: 1.0325x; 1.0325x over previous
//
#include <hip/hip_runtime.h>

#define Bsz 512
#define Ssz 512
#define Isz 32
#define Hsz 128
#define BB  2
#define LOG2E 1.44269504088896340736f

typedef __attribute__((ext_vector_type(8))) short bf16x8;
typedef __attribute__((ext_vector_type(4))) float f32x4;

__device__ __forceinline__ unsigned short f2bf(float f){
  unsigned u = __float_as_uint(f);
  return (unsigned short)((u + 0x7FFFu + ((u >> 16) & 1u)) >> 16);
}
// pre-activation scaled by log2(e): sigmoid
__device__ __forceinline__ float sigm_p(float xp){
  return __builtin_amdgcn_rcpf(1.f + __builtin_amdgcn_exp2f(-xp));
}
// pre-activation scaled by 2*log2(e): tanh
__device__ __forceinline__ float tanh_p(float xp2){
  return 1.f - 2.f * __builtin_amdgcn_rcpf(1.f + __builtin_amdgcn_exp2f(xp2));
}
// 8 consecutive K-elements of W row, scaled, as bf16 B-fragment
__device__ __forceinline__ bf16x8 ldw(const float* p, float s){
  bf16x8 r;
#pragma unroll
  for (int e=0;e<8;++e) r[e] = (short)f2bf(p[e]*s);
  return r;
}
__device__ __forceinline__ bf16x8 ldws(const float* pa, const float* pb, float s){
  bf16x8 r;
#pragma unroll
  for (int e=0;e<8;++e) r[e] = (short)f2bf((pa[e]+pb[e])*s);
  return r;
}

__global__ __launch_bounds__(256, 1) void lstm_ae(
    const float* __restrict__ x,
    const float* __restrict__ eWih, const float* __restrict__ eWhh,
    const float* __restrict__ ebih, const float* __restrict__ ebhh,
    const float* __restrict__ dWih, const float* __restrict__ dWhh,
    const float* __restrict__ dbih, const float* __restrict__ dbhh,
    const float* __restrict__ fcW,  const float* __restrict__ fcb,
    float* __restrict__ out)
{
  // big: encoder = x slice as bf16 (first 64KB); decoder = frames fp32 (128KB)
  __shared__ __attribute__((aligned(16))) float big[2*Ssz*Isz];
  // gate scratch, intra-wave only: [wave][gate][pair 0..63]
  __shared__ __attribute__((aligned(16))) float sc[4*4*64];
  // ping-pong h: [parity][row 0..1][col 0..127] bf16
  __shared__ __attribute__((aligned(16))) unsigned short hbuf[2][2][Hsz];

  const int tid  = threadIdx.x;
  const int lane = tid & 63;
  const int wv   = tid >> 6;
  const int c16  = lane & 15;
  const int quad = lane >> 4;
  const int bg0  = blockIdx.x * BB;

  // activation pair owned by this lane: batch row ab, h-col ak
  const int ab = lane >> 5;
  const int kl = lane & 31;            // col within wave's 32-col slice
  const int ak = wv*32 + kl;           // 0..127

  // ---- one-time: stage x (2 rows x 512 t x 32) into LDS as bf16 ----
  unsigned short* xl = (unsigned short*)big;
#pragma unroll 4
  for (int i = tid*4; i < 2*Ssz*Isz; i += 256*4){
    f32x4 v = *(const f32x4*)(x + (size_t)(bg0 + (i>>14))*(Ssz*Isz) + (i & 16383));
    xl[i+0]=f2bf(v[0]); xl[i+1]=f2bf(v[1]); xl[i+2]=f2bf(v[2]); xl[i+3]=f2bf(v[3]);
  }
  ((unsigned short*)hbuf)[tid]     = 0;
  ((unsigned short*)hbuf)[tid+256] = 0;

  // ---- encoder weights -> registers ----
  // tile j = g*2 + half: covers gate-cols n = g*128 + wv*32 + half*16 + c16
  bf16x8 W[8][4], wx[8];
#pragma unroll
  for (int j=0;j<8;++j){
    int g = j>>1;
    int n = g*128 + wv*32 + (j&1)*16 + c16;
    float s = (g==2) ? 2.f*LOG2E : LOG2E;
#pragma unroll
    for (int kt=0;kt<4;++kt) W[j][kt] = ldw(eWhh + (size_t)n*Hsz + kt*32 + quad*8, s);
    wx[j] = ldw(eWih + (size_t)n*Isz + quad*8, s);
  }
  // per-lane act biases (4 gates at col ak), scale folded
  float b_i = (ebih[0*Hsz+ak]+ebhh[0*Hsz+ak])*LOG2E;
  float b_f = (ebih[1*Hsz+ak]+ebhh[1*Hsz+ak])*LOG2E;
  float b_g = (ebih[2*Hsz+ak]+ebhh[2*Hsz+ak])*(2.f*LOG2E);
  float b_o = (ebih[3*Hsz+ak]+ebhh[3*Hsz+ak])*LOG2E;

  float cst = 0.f;                     // cell state for (ab, ak), in-lane
  const int hrow = c16 & 1;            // A-frag row select (rows>=2 are don't-care)

  auto ld_ah = [&](int rp, bf16x8* ah){
    const unsigned short* hb = &hbuf[rp][hrow][0];
#pragma unroll
    for (int kt=0;kt<4;++kt) ah[kt] = *(const bf16x8*)(hb + kt*32 + quad*8);
  };
  auto scatter = [&](f32x4* acc){      // quad0 -> sc (intra-wave, no barrier)
    if (quad == 0){
      float* s0 = sc + wv*256 + c16;
#pragma unroll
      for (int j=0;j<8;++j){
        float* p = s0 + (j>>1)*64 + (j&1)*16;
        p[0]  = acc[j][0];
        p[32] = acc[j][1];
      }
    }
  };
  auto act = [&](int wp, bool upd){    // all 64 lanes, 1 pair each
    const float* s0 = sc + wv*256 + lane;
    float pi = s0[0]   + b_i;
    float pf = s0[64]  + b_f;
    float pg = s0[128] + b_g;
    float po = s0[192] + b_o;
    float iv = sigm_p(pi), fv = sigm_p(pf), ov = sigm_p(po);
    float gv = tanh_p(pg);
    float cn = fv*cst + iv*gv;
    if (upd) cst = cn;
    float hh = ov * tanh_p(cn*(2.f*LOG2E));
    hbuf[wp][ab][ak] = f2bf(hh);
  };

  __syncthreads();   // x staged, hbuf[0] zeroed

  // ---------------- encoder ----------------
  int par = 0;
  for (int t=0; t<Ssz; ++t){
    bf16x8 ah[4]; ld_ah(par, ah);
    bf16x8 ax = *(const bf16x8*)(xl + hrow*(Ssz*Isz) + t*Isz + quad*8);
    f32x4 acc[8];
    f32x4 z = {0.f,0.f,0.f,0.f};
#pragma unroll
    for (int j=0;j<8;++j) acc[j] = z;
#pragma unroll
    for (int j=0;j<8;++j){
#pragma unroll
      for (int kt=0;kt<4;++kt)
        acc[j] = __builtin_amdgcn_mfma_f32_16x16x32_bf16(ah[kt], W[j][kt], acc[j], 0,0,0);
      acc[j] = __builtin_amdgcn_mfma_f32_16x16x32_bf16(ax, wx[j], acc[j], 0,0,0);
    }
    scatter(acc);
    act(par^1, true);
    __syncthreads();
    par ^= 1;
  }

  // ---------------- decoder ----------------
  float d_i = (dbih[0*Hsz+ak]+dbhh[0*Hsz+ak])*LOG2E;
  float d_f = (dbih[1*Hsz+ak]+dbhh[1*Hsz+ak])*LOG2E;
  float d_g = (dbih[2*Hsz+ak]+dbhh[2*Hsz+ak])*(2.f*LOG2E);
  float d_o = (dbih[3*Hsz+ak]+dbhh[3*Hsz+ak])*LOG2E;
  b_i=d_i; b_f=d_f; b_g=d_g; b_o=d_o;

  // step 0: inp=0, h=enc_h -> gates = enc_h @ dWhh^T + b   (cst stays enc_c)
#pragma unroll
  for (int j=0;j<8;++j){
    int g = j>>1;
    int n = g*128 + wv*32 + (j&1)*16 + c16;
    float s = (g==2) ? 2.f*LOG2E : LOG2E;
#pragma unroll
    for (int kt=0;kt<4;++kt) W[j][kt] = ldw(dWhh + (size_t)n*Hsz + kt*32 + quad*8, s);
  }
  {
    bf16x8 ah[4]; ld_ah(par, ah);
    f32x4 acc[8];
    f32x4 z = {0.f,0.f,0.f,0.f};
#pragma unroll
    for (int j=0;j<8;++j) acc[j] = z;
#pragma unroll
    for (int j=0;j<8;++j)
#pragma unroll
      for (int kt=0;kt<4;++kt)
        acc[j] = __builtin_amdgcn_mfma_f32_16x16x32_bf16(ah[kt], W[j][kt], acc[j], 0,0,0);
    scatter(acc);
    act(par^1, false);
    __syncthreads();
    par ^= 1;
  }

  // steps >=1: inp == h -> gates = h @ (dWih+dWhh)^T + b
#pragma unroll
  for (int j=0;j<8;++j){
    int g = j>>1;
    int n = g*128 + wv*32 + (j&1)*16 + c16;
    float s = (g==2) ? 2.f*LOG2E : LOG2E;
#pragma unroll
    for (int kt=0;kt<4;++kt)
      W[j][kt] = ldws(dWih + (size_t)n*Hsz + kt*32 + quad*8,
                      dWhh + (size_t)n*Hsz + kt*32 + quad*8, s);
  }
  bf16x8 wf[4];
  float bias_f = 0.f;
  if (wv < 2){
    int n = wv*16 + c16;
#pragma unroll
    for (int kt=0;kt<4;++kt) wf[kt] = ldw(fcW + (size_t)n*Hsz + kt*32 + quad*8, 1.f);
    bias_f = fcb[n];
  }
  float* fr = big;   // frames fp32: [b][t*32 + n]

  for (int t=1; t<Ssz; ++t){
    bf16x8 ah[4]; ld_ah(par, ah);
    if (wv < 2){
      f32x4 fa = {bias_f,bias_f,bias_f,bias_f};
#pragma unroll
      for (int kt=0;kt<4;++kt)
        fa = __builtin_amdgcn_mfma_f32_16x16x32_bf16(ah[kt], wf[kt], fa, 0,0,0);
      if (quad == 0){
        fr[           (t-1)*Isz + wv*16 + c16] = fa[0];
        fr[Ssz*Isz +  (t-1)*Isz + wv*16 + c16] = fa[1];
      }
    }
    f32x4 acc[8];
    f32x4 z = {0.f,0.f,0.f,0.f};
#pragma unroll
    for (int j=0;j<8;++j) acc[j] = z;
#pragma unroll
    for (int j=0;j<8;++j)
#pragma unroll
      for (int kt=0;kt<4;++kt)
        acc[j] = __builtin_amdgcn_mfma_f32_16x16x32_bf16(ah[kt], W[j][kt], acc[j], 0,0,0);
    scatter(acc);
    act(par^1, false);
    __syncthreads();
    par ^= 1;
  }

  // epilogue: frame s=511 from h(511)
  {
    bf16x8 ah[4]; ld_ah(par, ah);
    if (wv < 2){
      f32x4 fa = {bias_f,bias_f,bias_f,bias_f};
#pragma unroll
      for (int kt=0;kt<4;++kt)
        fa = __builtin_amdgcn_mfma_f32_16x16x32_bf16(ah[kt], wf[kt], fa, 0,0,0);
      if (quad == 0){
        fr[          (Ssz-1)*Isz + wv*16 + c16] = fa[0];
        fr[Ssz*Isz + (Ssz-1)*Isz + wv*16 + c16] = fa[1];
      }
    }
  }
  __syncthreads();

  // bulk frame store (coalesced)
#pragma unroll 4
  for (int i = tid*4; i < 2*Ssz*Isz; i += 256*4){
    f32x4 v = *(const f32x4*)(big + i);
    *(f32x4*)(out + (size_t)(bg0 + (i>>14))*(Ssz*Isz) + (i & 16383)) = v;
  }
}

extern "C" void kernel_launch(void* const* d_in, const int* in_sizes, int n_in,
                              void* d_out, int out_size, void* d_ws, size_t ws_size,
                              hipStream_t stream) {
  const float* x    = (const float*)d_in[0];
  const float* eWih = (const float*)d_in[1];
  const float* eWhh = (const float*)d_in[2];
  const float* ebih = (const float*)d_in[3];
  const float* ebhh = (const float*)d_in[4];
  const float* dWih = (const float*)d_in[5];
  const float* dWhh = (const float*)d_in[6];
  const float* dbih = (const float*)d_in[7];
  const float* dbhh = (const float*)d_in[8];
  const float* fcW  = (const float*)d_in[9];
  const float* fcb  = (const float*)d_in[10];
  float* outp = (float*)d_out;
  (void)d_ws; (void)ws_size; (void)in_sizes; (void)n_in; (void)out_size;
  lstm_ae<<<dim3(Bsz/BB), dim3(256), 0, stream>>>(
      x, eWih, eWhh, ebih, ebhh, dWih, dWhh, dbih, dbhh, fcW, fcb, outp);
}